// Round 17
// baseline (102.378 us; speedup 1.0000x reference)
//
#include <hip/hip_runtime.h>
#include <hip/hip_bf16.h>
#include <hip/hip_fp16.h>

#define NN   8
#define CIN  128
#define HH   96
#define WW   96
#define COUT 256
#define KK   9      // 3x3
#define HO   96
#define WO   96
#define PTOT (NN*HO*WO)          // 73728
#define BM   64                  // positions per block
#define KTOT (CIN*KK)            // 1152
#define KSTEPS (KTOT/32)         // 36

typedef _Float16 f16x8 __attribute__((ext_vector_type(8)));
typedef float f32x4  __attribute__((ext_vector_type(4)));

// ---------------------------------------------------------------------------
// helpers
// ---------------------------------------------------------------------------
__device__ __forceinline__ __half2 u2h2(unsigned u) {
    union { unsigned u; __half2 h; } c; c.u = u; return c.h;
}
__device__ __forceinline__ unsigned h22u(__half2 h) {
    union { unsigned u; __half2 h; } c; c.h = h; return c.u;
}
__device__ __forceinline__ unsigned pack_h2(float a, float b) {
    auto v = __builtin_amdgcn_cvt_pkrtz(a, b);        // v_cvt_pkrtz_f16_f32
    union { decltype(v) h; unsigned u; } c; c.h = v; return c.u;
}

// ---------------------------------------------------------------------------
// Preprocess 1: input fp32 NCHW -> fp16 NHWC  (one block per (n,y) plane)
// ---------------------------------------------------------------------------
__global__ __launch_bounds__(256) void to_nhwc_f16(const float* __restrict__ in,
                                                   unsigned short* __restrict__ outp) {
    __shared__ float tile[CIN * 97];
    const int ny = blockIdx.x;                // n*96 + y
    const int n = ny / HH, y = ny - n * HH;
    const float* src = in + (size_t)n * CIN * HH * WW + (size_t)y * WW;
    for (int i = threadIdx.x; i < CIN * WW; i += 256) {
        int c = i / WW, x = i - c * WW;
        tile[c * 97 + x] = src[(size_t)c * HH * WW + x];
    }
    __syncthreads();
    unsigned* dst = (unsigned*)(outp + (size_t)ny * WW * CIN);
    for (int i = threadIdx.x; i < (WW * CIN) / 2; i += 256) {
        int c2 = (i & 63) * 2;
        int x  = i >> 6;
        dst[x * (CIN / 2) + (c2 >> 1)] = pack_h2(tile[c2 * 97 + x], tile[(c2 + 1) * 97 + x]);
    }
}

// ---------------------------------------------------------------------------
// Preprocess 2: weight fp32 [Cout][Cin][9] -> fp16 fragment-packed
// ---------------------------------------------------------------------------
__global__ __launch_bounds__(256) void w_pack(const float* __restrict__ w,
                                              unsigned short* __restrict__ wp) {
    int idx = blockIdx.x * 256 + threadIdx.x;
    if (idx >= KSTEPS * 16 * 64 * 8) return;
    int j  = idx & 7;
    int l  = (idx >> 3) & 63;
    int cb = (idx >> 9) & 15;
    int ks = idx >> 13;
    int co  = cb * 16 + (l & 15);
    int kg  = ks * 32 + ((l >> 4) * 8) + j;
    int tap = kg >> 7;
    int cin = kg & 127;
    _Float16 h = (_Float16)w[((size_t)co * CIN + cin) * KK + tap];
    wp[idx] = *(unsigned short*)&h;
}

// ---------------------------------------------------------------------------
// Main: implicit GEMM with PRODUCER/CONSUMER WAVE SPECIALIZATION.
// 512 thr = 4 producer waves (gather only, no acc live; batch-issue all 16
// corner loads per tap -> one latency exposure) + 4 consumer waves (MFMA
// only, acc[4][4]; no gather state). Separate loops, matched barrier counts
// (10 each after geom barrier). Register budget by ROLE sidesteps the
// r4/7/9 spill law (same-wave pipelining: acc+gather state > 128 regs).
// (512,4): 128-reg cap, 2 blocks/CU. Champion facts kept: fp16 packed blend,
// (row&15)<<4 swizzle (0 conflicts), geometry in LDS (r13), BM=64 (r12),
// chunk=t&15/pos=t>>4 coalescing (r15), XCD-chunked block swizzle.
// Spill tripwire: WRITE >> 90MB => revert to champion.
// LDS: geom [0,6912) | buf0 [6912,23296) | buf1 [23296,39680)
// ---------------------------------------------------------------------------
#define GEOM_BYTES 6912
#define LDS_BYTES  39680
#define BUF0 6912
#define BUF1 23296

__global__ __launch_bounds__(512, 4) void deform_mfma(
    const unsigned short* __restrict__ imgB,   // fp16 NHWC
    const float*          __restrict__ off,    // [N][18][96][96]
    const unsigned short* __restrict__ wPack,  // fp16 frag-packed
    float*                __restrict__ out)    // [N][256][96][96]
{
    __shared__ __align__(16) char smem[LDS_BYTES];
    unsigned* gOff = (unsigned*)smem;                 // [576]
    unsigned* gW0  = (unsigned*)(smem + 2304);        // [576] (w00,w01) fp16
    unsigned* gW1  = (unsigned*)(smem + 4608);        // [576] (w10,w11) fp16

    const int t    = threadIdx.x;                     // 0..511
    const int lane = t & 63;
    const int wv   = t >> 6;                          // 0..7

    // XCD-chunked swizzle (bijective: 1152 % 8 == 0).
    const int bid  = ((blockIdx.x & 7) * ((PTOT / BM) >> 3)) + (blockIdx.x >> 3);

    const int p0   = bid * BM;
    const int nb   = p0 / (HO * WO);
    const int p0rem = p0 - nb * (HO * WO);

    // ---- one-time geometry precompute for all (tap,pos) : all 512 thr ----
    for (int i = t; i < KK * BM; i += 512) {
        int tap = i >> 6, m = i & 63;
        int plin = p0rem + m;
        int ho = plin / WO, wo = plin - ho * WO;
        int kh = tap / 3, kw = tap - kh * 3;
        const float* ob = off + ((size_t)nb * 2 * KK + 2 * tap) * (HO * WO) + plin;
        float py = (float)(ho - 1 + kh) + ob[0];
        float px = (float)(wo - 1 + kw) + ob[HO * WO];
        float y0f = floorf(py), x0f = floorf(px);
        float ly = py - y0f, lx = px - x0f;
        int y0 = (int)y0f, x0 = (int)x0f;

        bool vy0 = (unsigned)y0 < (unsigned)HH;
        bool vy1 = (unsigned)(y0 + 1) < (unsigned)HH;
        bool vx0 = (unsigned)x0 < (unsigned)WW;
        bool vx1 = (unsigned)(x0 + 1) < (unsigned)WW;
        int yc0 = min(max(y0, 0), HH - 1);
        int yc1 = min(max(y0 + 1, 0), HH - 1);
        int xc0 = min(max(x0, 0), WW - 1);
        int xc1 = min(max(x0 + 1, 0), WW - 1);

        float w11 = ly * lx;
        float w10 = ly - w11;
        float w01 = lx - w11;
        float w00 = 1.f - ly - lx + w11;
        w00 = (vy0 && vx0) ? w00 : 0.f;
        w01 = (vy0 && vx1) ? w01 : 0.f;
        w10 = (vy1 && vx0) ? w10 : 0.f;
        w11 = (vy1 && vx1) ? w11 : 0.f;

        unsigned byte00 = (unsigned)(yc0 * WW + xc0) * (CIN * 2);   // < 2^22
        unsigned xs = (xc1 != xc0) ? 1u : 0u;
        unsigned ys = (yc1 != yc0) ? 1u : 0u;
        gOff[i] = byte00 | (xs << 22) | (ys << 23);
        gW0[i]  = pack_h2(w00, w01);
        gW1[i]  = pack_h2(w10, w11);
    }

    const char* imgN = (const char*)(imgB + (size_t)nb * (HH * WW) * CIN);

    __syncthreads();                 // geom visible

    if (wv < 4) {
        // ================= PRODUCER waves =================
        // 256 threads cover 1024 items/tap (4 each). All 16 corner loads
        // issued before any blend -> single latency exposure per tap.
        auto gather = [&](int tap, char* bufw) {
            uint4 r[4][4];
            unsigned w0p[4], w1p[4];
            int byt[4];
#pragma unroll
            for (int it = 0; it < 4; ++it) {
                int item  = t + it * 256;        // 0..1023
                int pos   = item >> 4;           // 0..63
                int chunk = item & 15;           // 8-cin chunk
                int gi    = tap * 64 + pos;
                unsigned ofl = gOff[gi];
                w0p[it] = gW0[gi];
                w1p[it] = gW1[gi];
                unsigned a00 = (ofl & 0x3fffffu) + (unsigned)(chunk * 16);
                unsigned dx  = (ofl >> 14) & 0x100u;            // xs*256
                unsigned dy  = ((ofl >> 23) & 1u) * 24576u;     // ys*96*256
                r[it][0] = *(const uint4*)(imgN + a00);
                r[it][1] = *(const uint4*)(imgN + a00 + dx);
                r[it][2] = *(const uint4*)(imgN + a00 + dy);
                r[it][3] = *(const uint4*)(imgN + a00 + dy + dx);
                int byte = pos * 256 + chunk * 16;
                byt[it] = byte ^ ((pos & 15) << 4);             // widened swizzle
            }
#pragma unroll
            for (int it = 0; it < 4; ++it) {
                unsigned u00 = w0p[it] & 0xffffu;   u00 |= u00 << 16;
                unsigned u01 = w0p[it] >> 16;       u01 |= u01 << 16;
                unsigned u10 = w1p[it] & 0xffffu;   u10 |= u10 << 16;
                unsigned u11 = w1p[it] >> 16;       u11 |= u11 << 16;
                __half2 w00s = u2h2(u00), w01s = u2h2(u01);
                __half2 w10s = u2h2(u10), w11s = u2h2(u11);

                unsigned pk[4];
                __half2 s;
                s = __hmul2(u2h2(r[it][3].x), w11s);
                s = __hfma2(u2h2(r[it][2].x), w10s, s);
                s = __hfma2(u2h2(r[it][1].x), w01s, s);
                s = __hfma2(u2h2(r[it][0].x), w00s, s);
                pk[0] = h22u(s);
                s = __hmul2(u2h2(r[it][3].y), w11s);
                s = __hfma2(u2h2(r[it][2].y), w10s, s);
                s = __hfma2(u2h2(r[it][1].y), w01s, s);
                s = __hfma2(u2h2(r[it][0].y), w00s, s);
                pk[1] = h22u(s);
                s = __hmul2(u2h2(r[it][3].z), w11s);
                s = __hfma2(u2h2(r[it][2].z), w10s, s);
                s = __hfma2(u2h2(r[it][1].z), w01s, s);
                s = __hfma2(u2h2(r[it][0].z), w00s, s);
                pk[2] = h22u(s);
                s = __hmul2(u2h2(r[it][3].w), w11s);
                s = __hfma2(u2h2(r[it][2].w), w10s, s);
                s = __hfma2(u2h2(r[it][1].w), w01s, s);
                s = __hfma2(u2h2(r[it][0].w), w00s, s);
                pk[3] = h22u(s);

                *(uint4*)(bufw + byt[it]) = make_uint4(pk[0], pk[1], pk[2], pk[3]);
            }
        };

        gather(0, smem + BUF0);
        for (int tap = 0; tap < KK; ++tap) {
            __syncthreads();             // buf[tap&1] handed to consumers
            if (tap + 1 < KK) gather(tap + 1, smem + ((tap & 1) ? BUF0 : BUF1));
        }
        __syncthreads();                 // pre-epilogue (matches consumer)
        // producers idle through epilogue
    } else {
        // ================= CONSUMER waves =================
        const int cw = wv - 4;           // 0..3 -> Cout range cw*64
        f32x4 acc[4][4];
#pragma unroll
        for (int mf = 0; mf < 4; ++mf)
#pragma unroll
            for (int nf = 0; nf < 4; ++nf) acc[mf][nf] = (f32x4)0.f;

        for (int tap = 0; tap < KK; ++tap) {
            __syncthreads();             // buf[tap&1] fully written
            const char* bufr = smem + ((tap & 1) ? BUF1 : BUF0);
#pragma unroll
            for (int cs = 0; cs < 4; ++cs) {
                int ks = tap * 4 + cs;
                f16x8 a[4], b[4];
#pragma unroll
                for (int mf = 0; mf < 4; ++mf) {
                    int row  = mf * 16 + (lane & 15);
                    int byte = row * 256 + cs * 64 + ((lane >> 4) * 16);
                    byte ^= (row & 15) << 4;              // widened swizzle
                    a[mf] = *(const f16x8*)(bufr + byte);
                }
#pragma unroll
                for (int nf = 0; nf < 4; ++nf) {
                    int tile = ks * 16 + (cw * 4 + nf);
                    b[nf] = *(const f16x8*)(wPack + (size_t)tile * 512 + lane * 8);
                }
                __builtin_amdgcn_s_setprio(1);
#pragma unroll
                for (int mf = 0; mf < 4; ++mf)
#pragma unroll
                    for (int nf = 0; nf < 4; ++nf)
                        acc[mf][nf] = __builtin_amdgcn_mfma_f32_16x16x32_f16(
                            a[mf], b[nf], acc[mf][nf], 0, 0, 0);
                __builtin_amdgcn_s_setprio(0);
            }
        }
        __syncthreads();                 // all taps done; smem reusable

        // ---- epilogue: per-consumer-wave LDS transpose -> row writes ----
        float* cT = (float*)smem + cw * (64 * 20);        // 5120 B per wave
        const int colbase = lane & 15;
        const int rowq    = lane >> 4;                    // 0..3
        float* outbase = out + ((size_t)nb * COUT + cw * 64 + lane) * (HO * WO) + p0rem;
#pragma unroll
        for (int mf = 0; mf < 4; ++mf) {
#pragma unroll
            for (int nf = 0; nf < 4; ++nf) {
                int co = nf * 16 + colbase;
                *(f32x4*)&cT[co * 20 + rowq * 4] = acc[mf][nf];
            }
            asm volatile("s_waitcnt lgkmcnt(0)" ::: "memory");
            __builtin_amdgcn_sched_barrier(0);
#pragma unroll
            for (int q = 0; q < 4; ++q) {
                f32x4 v = *(f32x4*)&cT[lane * 20 + q * 4];
                *(float4*)(outbase + mf * 16 + q * 4) = *(float4*)&v;
            }
        }
    }
}

// ---------------------------------------------------------------------------
// Fallback (fp32, no workspace) — correctness insurance if ws is too small.
// ---------------------------------------------------------------------------
__global__ __launch_bounds__(256) void deform_fallback(const float* __restrict__ img,
                                                       const float* __restrict__ off,
                                                       const float* __restrict__ wgt,
                                                       float* __restrict__ out) {
    __shared__ float samp[8][CIN];
    const int tid = threadIdx.x;
    const int p0  = blockIdx.x * 8;
    const int n   = p0 / (HO * WO);
    const int rem = p0 % (HO * WO);
    const int ho  = rem / WO;
    const int wo0 = rem % WO;
    float acc[8];
#pragma unroll
    for (int t = 0; t < 8; ++t) acc[t] = 0.f;
    for (int k = 0; k < KK; ++k) {
        __syncthreads();
        const int kh = k / 3, kw = k % 3;
#pragma unroll
        for (int it = 0; it < 4; ++it) {
            int idx = tid + it * 256;
            int t   = idx >> 7;
            int c   = idx & (CIN - 1);
            int wo  = wo0 + t;
            float dy = off[(((size_t)n * 2 * KK + 2 * k) * HO + ho) * WO + wo];
            float dx = off[(((size_t)n * 2 * KK + 2 * k + 1) * HO + ho) * WO + wo];
            float py = (float)(ho - 1 + kh) + dy;
            float px = (float)(wo - 1 + kw) + dx;
            float y0f = floorf(py), x0f = floorf(px);
            float ly = py - y0f, lx = px - x0f;
            int y0 = (int)y0f, x0 = (int)x0f;
            float v00 = 0.f, v01 = 0.f, v10 = 0.f, v11 = 0.f;
            const float* base = img + ((size_t)n * CIN + c) * HH * WW;
            if ((unsigned)y0 < (unsigned)HH) {
                const float* row = base + (size_t)y0 * WW;
                if ((unsigned)x0 < (unsigned)WW)       v00 = row[x0];
                if ((unsigned)(x0 + 1) < (unsigned)WW) v01 = row[x0 + 1];
            }
            if ((unsigned)(y0 + 1) < (unsigned)HH) {
                const float* row = base + (size_t)(y0 + 1) * WW;
                if ((unsigned)x0 < (unsigned)WW)       v10 = row[x0];
                if ((unsigned)(x0 + 1) < (unsigned)WW) v11 = row[x0 + 1];
            }
            float top = v00 + lx * (v01 - v00);
            float bot = v10 + lx * (v11 - v10);
            samp[t][c] = top + ly * (bot - top);
        }
        __syncthreads();
        const float* wk = wgt + (size_t)tid * CIN * KK + k;
        for (int c = 0; c < CIN; c += 4) {
            float w0 = wk[(c + 0) * KK], w1 = wk[(c + 1) * KK];
            float w2 = wk[(c + 2) * KK], w3 = wk[(c + 3) * KK];
#pragma unroll
            for (int t = 0; t < 8; ++t) {
                const float4 s = *(const float4*)&samp[t][c];
                acc[t] = fmaf(s.x, w0, acc[t]);
                acc[t] = fmaf(s.y, w1, acc[t]);
                acc[t] = fmaf(s.z, w2, acc[t]);
                acc[t] = fmaf(s.w, w3, acc[t]);
            }
        }
    }
#pragma unroll
    for (int t = 0; t < 8; ++t)
        out[(((size_t)n * COUT + tid) * HO + ho) * WO + wo0 + t] = acc[t];
}

extern "C" void kernel_launch(void* const* d_in, const int* in_sizes, int n_in,
                              void* d_out, int out_size, void* d_ws, size_t ws_size,
                              hipStream_t stream) {
    const float* inp = (const float*)d_in[0];
    const float* off = (const float*)d_in[1];
    const float* wgt = (const float*)d_in[2];
    float* out = (float*)d_out;

    const size_t img_bytes = (size_t)NN * HH * WW * CIN * 2;
    const size_t wp_bytes  = (size_t)KSTEPS * 16 * 64 * 8 * 2;

    if (ws_size >= img_bytes + wp_bytes) {
        unsigned short* imgB  = (unsigned short*)d_ws;
        unsigned short* wPack = (unsigned short*)((char*)d_ws + img_bytes);
        to_nhwc_f16<<<NN * HH, 256, 0, stream>>>(inp, imgB);
        w_pack<<<(KSTEPS * 16 * 64 * 8) / 256, 256, 0, stream>>>(wgt, wPack);
        deform_mfma<<<PTOT / BM, 512, 0, stream>>>(imgB, off, wPack, out);
    } else {
        deform_fallback<<<PTOT / 8, 256, 0, stream>>>(inp, off, wgt, out);
    }
}

// Round 18
// 95.256 us; speedup vs baseline: 1.0748x; 1.0748x over previous
//
#include <hip/hip_runtime.h>
#include <hip/hip_bf16.h>
#include <hip/hip_fp16.h>

#define NN   8
#define CIN  128
#define HH   96
#define WW   96
#define COUT 256
#define KK   9      // 3x3
#define HO   96
#define WO   96
#define PTOT (NN*HO*WO)          // 73728
#define BM   64                  // positions per block
#define KTOT (CIN*KK)            // 1152
#define KSTEPS (KTOT/32)         // 36

typedef _Float16 f16x8 __attribute__((ext_vector_type(8)));
typedef float f32x4  __attribute__((ext_vector_type(4)));

// ---------------------------------------------------------------------------
// helpers
// ---------------------------------------------------------------------------
__device__ __forceinline__ __half2 u2h2(unsigned u) {
    union { unsigned u; __half2 h; } c; c.u = u; return c.h;
}
__device__ __forceinline__ unsigned h22u(__half2 h) {
    union { unsigned u; __half2 h; } c; c.h = h; return c.u;
}
__device__ __forceinline__ unsigned pack_h2(float a, float b) {
    auto v = __builtin_amdgcn_cvt_pkrtz(a, b);        // v_cvt_pkrtz_f16_f32
    union { decltype(v) h; unsigned u; } c; c.h = v; return c.u;
}

// ---------------------------------------------------------------------------
// Preprocess 1: input fp32 NCHW -> fp16 NHWC  (one block per (n,y) plane)
// ---------------------------------------------------------------------------
__global__ __launch_bounds__(256) void to_nhwc_f16(const float* __restrict__ in,
                                                   unsigned short* __restrict__ outp) {
    __shared__ float tile[CIN * 97];
    const int ny = blockIdx.x;                // n*96 + y
    const int n = ny / HH, y = ny - n * HH;
    const float* src = in + (size_t)n * CIN * HH * WW + (size_t)y * WW;
    for (int i = threadIdx.x; i < CIN * WW; i += 256) {
        int c = i / WW, x = i - c * WW;
        tile[c * 97 + x] = src[(size_t)c * HH * WW + x];
    }
    __syncthreads();
    unsigned* dst = (unsigned*)(outp + (size_t)ny * WW * CIN);
    for (int i = threadIdx.x; i < (WW * CIN) / 2; i += 256) {
        int c2 = (i & 63) * 2;
        int x  = i >> 6;
        dst[x * (CIN / 2) + (c2 >> 1)] = pack_h2(tile[c2 * 97 + x], tile[(c2 + 1) * 97 + x]);
    }
}

// ---------------------------------------------------------------------------
// Preprocess 2: weight fp32 [Cout][Cin][9] -> fp16 fragment-packed
// ---------------------------------------------------------------------------
__global__ __launch_bounds__(256) void w_pack(const float* __restrict__ w,
                                              unsigned short* __restrict__ wp) {
    int idx = blockIdx.x * 256 + threadIdx.x;
    if (idx >= KSTEPS * 16 * 64 * 8) return;
    int j  = idx & 7;
    int l  = (idx >> 3) & 63;
    int cb = (idx >> 9) & 15;
    int ks = idx >> 13;
    int co  = cb * 16 + (l & 15);
    int kg  = ks * 32 + ((l >> 4) * 8) + j;
    int tap = kg >> 7;
    int cin = kg & 127;
    _Float16 h = (_Float16)w[((size_t)co * CIN + cin) * KK + tap];
    wp[idx] = *(unsigned short*)&h;
}

// ---------------------------------------------------------------------------
// Main: implicit GEMM, 512 thr / 8 waves; wave = M64 x N32 (acc[4][2]=32).
// CHAMPION (rounds 11/16, 86.7us main): fp16 packed blend, widened
// (row&15)<<4 swizzle (0 bank conflicts), geometry in LDS, XCD-chunked
// block swizzle. Structural verdicts (all regressed vs this):
//   r12 BM=32: barrier amortization + B-traffic loss. Keep BM=64/8 waves.
//   r13 global geom table: overflows per-XCD 4MB L2 (FETCH +54%). Keep LDS.
//   r14 batched 8-load issue @(512,5): occupancy 48->35%. Keep (512,6).
//   r15 chunk-pair gather: strided corner loads halve coalescing. Keep
//       chunk=t&15 / pos=t>>4 mapping (contiguous 256B per position).
//   r17 producer/consumer wave split @(512,4): duty-cycle + residency loss.
//   r4/7/9 same-wave cross-cluster pipelining: VGPR spill (WRITE explosion).
// Latency-bound plateau: MfmaUtil ~21%, VALU ~24%, HBM ~17%, conflicts 0.
// LDS: geom [0,6912) | buf0 [6912,23296) | buf1 [23296,39680)
// ---------------------------------------------------------------------------
#define GEOM_BYTES 6912
#define LDS_BYTES  39680
#define BUF0 6912
#define BUF1 23296

__global__ __launch_bounds__(512, 6) void deform_mfma(
    const unsigned short* __restrict__ imgB,   // fp16 NHWC
    const float*          __restrict__ off,    // [N][18][96][96]
    const unsigned short* __restrict__ wPack,  // fp16 frag-packed
    float*                __restrict__ out)    // [N][256][96][96]
{
    __shared__ __align__(16) char smem[LDS_BYTES];
    unsigned* gOff = (unsigned*)smem;                 // [576]
    unsigned* gW0  = (unsigned*)(smem + 2304);        // [576] (w00,w01) fp16
    unsigned* gW1  = (unsigned*)(smem + 4608);        // [576] (w10,w11) fp16

    const int t    = threadIdx.x;                     // 0..511
    const int lane = t & 63;
    const int wv   = t >> 6;                          // 0..7

    // XCD-chunked swizzle (bijective: 1152 % 8 == 0).
    const int bid  = ((blockIdx.x & 7) * ((PTOT / BM) >> 3)) + (blockIdx.x >> 3);

    const int p0   = bid * BM;
    const int nb   = p0 / (HO * WO);
    const int p0rem = p0 - nb * (HO * WO);

    // ---- one-time geometry precompute for all (tap,pos) ----
    for (int i = t; i < KK * BM; i += 512) {
        int tap = i >> 6, m = i & 63;
        int plin = p0rem + m;
        int ho = plin / WO, wo = plin - ho * WO;
        int kh = tap / 3, kw = tap - kh * 3;
        const float* ob = off + ((size_t)nb * 2 * KK + 2 * tap) * (HO * WO) + plin;
        float py = (float)(ho - 1 + kh) + ob[0];
        float px = (float)(wo - 1 + kw) + ob[HO * WO];
        float y0f = floorf(py), x0f = floorf(px);
        float ly = py - y0f, lx = px - x0f;
        int y0 = (int)y0f, x0 = (int)x0f;

        bool vy0 = (unsigned)y0 < (unsigned)HH;
        bool vy1 = (unsigned)(y0 + 1) < (unsigned)HH;
        bool vx0 = (unsigned)x0 < (unsigned)WW;
        bool vx1 = (unsigned)(x0 + 1) < (unsigned)WW;
        int yc0 = min(max(y0, 0), HH - 1);
        int yc1 = min(max(y0 + 1, 0), HH - 1);
        int xc0 = min(max(x0, 0), WW - 1);
        int xc1 = min(max(x0 + 1, 0), WW - 1);

        float w11 = ly * lx;
        float w10 = ly - w11;
        float w01 = lx - w11;
        float w00 = 1.f - ly - lx + w11;
        w00 = (vy0 && vx0) ? w00 : 0.f;
        w01 = (vy0 && vx1) ? w01 : 0.f;
        w10 = (vy1 && vx0) ? w10 : 0.f;
        w11 = (vy1 && vx1) ? w11 : 0.f;

        unsigned byte00 = (unsigned)(yc0 * WW + xc0) * (CIN * 2);   // < 2^22
        unsigned xs = (xc1 != xc0) ? 1u : 0u;
        unsigned ys = (yc1 != yc0) ? 1u : 0u;
        gOff[i] = byte00 | (xs << 22) | (ys << 23);
        gW0[i]  = pack_h2(w00, w01);
        gW1[i]  = pack_h2(w10, w11);
    }

    f32x4 acc[4][2];
#pragma unroll
    for (int mf = 0; mf < 4; ++mf)
#pragma unroll
        for (int nf = 0; nf < 2; ++nf) acc[mf][nf] = (f32x4)0.f;

    const char* imgN = (const char*)(imgB + (size_t)nb * (HH * WW) * CIN);

    // gather of samp[64 pos][128 cin] for one tap (geometry from LDS);
    // blend entirely in packed fp16 (v_pk_fma_f16 on loaded pairs).
    auto gather = [&](int tap, char* bufw) {
#pragma unroll
        for (int it = 0; it < 2; ++it) {
            int item  = t + it * 512;        // 0..1023
            int pos   = item >> 4;           // 0..63
            int chunk = item & 15;           // 8-cin chunk
            int gi    = tap * 64 + pos;

            unsigned ofl  = gOff[gi];
            unsigned w0pk = gW0[gi];
            unsigned w1pk = gW1[gi];

            unsigned a00 = (ofl & 0x3fffffu) + (unsigned)(chunk * 16);
            unsigned dx  = (ofl >> 14) & 0x100u;            // xs*256
            unsigned dy  = ((ofl >> 23) & 1u) * 24576u;     // ys*96*256

            uint4 r00 = *(const uint4*)(imgN + a00);
            uint4 r01 = *(const uint4*)(imgN + a00 + dx);
            uint4 r10 = *(const uint4*)(imgN + a00 + dy);
            uint4 r11 = *(const uint4*)(imgN + a00 + dy + dx);

            // splat packed fp16 weights
            unsigned u00 = w0pk & 0xffffu;      u00 |= u00 << 16;
            unsigned u01 = w0pk >> 16;          u01 |= u01 << 16;
            unsigned u10 = w1pk & 0xffffu;      u10 |= u10 << 16;
            unsigned u11 = w1pk >> 16;          u11 |= u11 << 16;
            __half2 w00s = u2h2(u00), w01s = u2h2(u01);
            __half2 w10s = u2h2(u10), w11s = u2h2(u11);

            unsigned pk[4];
            __half2 s;
            s = __hmul2(u2h2(r11.x), w11s);
            s = __hfma2(u2h2(r10.x), w10s, s);
            s = __hfma2(u2h2(r01.x), w01s, s);
            s = __hfma2(u2h2(r00.x), w00s, s);
            pk[0] = h22u(s);
            s = __hmul2(u2h2(r11.y), w11s);
            s = __hfma2(u2h2(r10.y), w10s, s);
            s = __hfma2(u2h2(r01.y), w01s, s);
            s = __hfma2(u2h2(r00.y), w00s, s);
            pk[1] = h22u(s);
            s = __hmul2(u2h2(r11.z), w11s);
            s = __hfma2(u2h2(r10.z), w10s, s);
            s = __hfma2(u2h2(r01.z), w01s, s);
            s = __hfma2(u2h2(r00.z), w00s, s);
            pk[2] = h22u(s);
            s = __hmul2(u2h2(r11.w), w11s);
            s = __hfma2(u2h2(r10.w), w10s, s);
            s = __hfma2(u2h2(r01.w), w01s, s);
            s = __hfma2(u2h2(r00.w), w00s, s);
            pk[3] = h22u(s);

            int byte = pos * 256 + chunk * 16;
            byte ^= (pos & 15) << 4;                      // widened swizzle
            *(uint4*)(bufw + byte) = make_uint4(pk[0], pk[1], pk[2], pk[3]);
        }
    };

    __syncthreads();                 // geom visible
    gather(0, smem + BUF0);

    for (int tap = 0; tap < KK; ++tap) {
        __syncthreads();             // buf[tap&1] fully written
        const char* bufr = smem + ((tap & 1) ? BUF1 : BUF0);

        // ---- 4 K-steps of MFMA on buf[tap&1] ----
#pragma unroll
        for (int cs = 0; cs < 4; ++cs) {
            int ks = tap * 4 + cs;
            f16x8 a[4], b[2];
#pragma unroll
            for (int mf = 0; mf < 4; ++mf) {
                int row  = mf * 16 + (lane & 15);
                int byte = row * 256 + cs * 64 + ((lane >> 4) * 16);
                byte ^= (row & 15) << 4;                  // widened swizzle
                a[mf] = *(const f16x8*)(bufr + byte);
            }
#pragma unroll
            for (int nf = 0; nf < 2; ++nf) {
                int tile = ks * 16 + (wv * 2 + nf);
                b[nf] = *(const f16x8*)(wPack + (size_t)tile * 512 + lane * 8);
            }
            __builtin_amdgcn_s_setprio(1);
#pragma unroll
            for (int mf = 0; mf < 4; ++mf)
#pragma unroll
                for (int nf = 0; nf < 2; ++nf)
                    acc[mf][nf] = __builtin_amdgcn_mfma_f32_16x16x32_f16(
                        a[mf], b[nf], acc[mf][nf], 0, 0, 0);
            __builtin_amdgcn_s_setprio(0);
        }

        // ---- overlap: gather next tap into the other buffer ----
        if (tap + 1 < KK) gather(tap + 1, smem + ((tap & 1) ? BUF0 : BUF1));
    }

    // ---- epilogue: per-wave, per-mf LDS transpose -> coalesced row writes ----
    __syncthreads();
    float* cT = (float*)smem + wv * (32 * 20);            // 2560 B per wave
    const int colbase = lane & 15;
    const int rowq    = lane >> 4;                        // 0..3
    const int co2     = lane & 31;
    const int half    = lane >> 5;                        // 0..1
    float* outbase = out + ((size_t)nb * COUT + wv * 32 + co2) * (HO * WO) + p0rem;
#pragma unroll
    for (int mf = 0; mf < 4; ++mf) {
#pragma unroll
        for (int nf = 0; nf < 2; ++nf) {
            int co = nf * 16 + colbase;
            *(f32x4*)&cT[co * 20 + rowq * 4] = acc[mf][nf];
        }
        asm volatile("s_waitcnt lgkmcnt(0)" ::: "memory");
        __builtin_amdgcn_sched_barrier(0);
        f32x4 v0 = *(f32x4*)&cT[co2 * 20 + half * 8];
        f32x4 v1 = *(f32x4*)&cT[co2 * 20 + half * 8 + 4];
        *(float4*)(outbase + mf * 16 + half * 8)     = *(float4*)&v0;
        *(float4*)(outbase + mf * 16 + half * 8 + 4) = *(float4*)&v1;
    }
}

// ---------------------------------------------------------------------------
// Fallback (fp32, no workspace) — correctness insurance if ws is too small.
// ---------------------------------------------------------------------------
__global__ __launch_bounds__(256) void deform_fallback(const float* __restrict__ img,
                                                       const float* __restrict__ off,
                                                       const float* __restrict__ wgt,
                                                       float* __restrict__ out) {
    __shared__ float samp[8][CIN];
    const int tid = threadIdx.x;
    const int p0  = blockIdx.x * 8;
    const int n   = p0 / (HO * WO);
    const int rem = p0 % (HO * WO);
    const int ho  = rem / WO;
    const int wo0 = rem % WO;
    float acc[8];
#pragma unroll
    for (int t = 0; t < 8; ++t) acc[t] = 0.f;
    for (int k = 0; k < KK; ++k) {
        __syncthreads();
        const int kh = k / 3, kw = k % 3;
#pragma unroll
        for (int it = 0; it < 4; ++it) {
            int idx = tid + it * 256;
            int t   = idx >> 7;
            int c   = idx & (CIN - 1);
            int wo  = wo0 + t;
            float dy = off[(((size_t)n * 2 * KK + 2 * k) * HO + ho) * WO + wo];
            float dx = off[(((size_t)n * 2 * KK + 2 * k + 1) * HO + ho) * WO + wo];
            float py = (float)(ho - 1 + kh) + dy;
            float px = (float)(wo - 1 + kw) + dx;
            float y0f = floorf(py), x0f = floorf(px);
            float ly = py - y0f, lx = px - x0f;
            int y0 = (int)y0f, x0 = (int)x0f;
            float v00 = 0.f, v01 = 0.f, v10 = 0.f, v11 = 0.f;
            const float* base = img + ((size_t)n * CIN + c) * HH * WW;
            if ((unsigned)y0 < (unsigned)HH) {
                const float* row = base + (size_t)y0 * WW;
                if ((unsigned)x0 < (unsigned)WW)       v00 = row[x0];
                if ((unsigned)(x0 + 1) < (unsigned)WW) v01 = row[x0 + 1];
            }
            if ((unsigned)(y0 + 1) < (unsigned)HH) {
                const float* row = base + (size_t)(y0 + 1) * WW;
                if ((unsigned)x0 < (unsigned)WW)       v10 = row[x0];
                if ((unsigned)(x0 + 1) < (unsigned)WW) v11 = row[x0 + 1];
            }
            float top = v00 + lx * (v01 - v00);
            float bot = v10 + lx * (v11 - v10);
            samp[t][c] = top + ly * (bot - top);
        }
        __syncthreads();
        const float* wk = wgt + (size_t)tid * CIN * KK + k;
        for (int c = 0; c < CIN; c += 4) {
            float w0 = wk[(c + 0) * KK], w1 = wk[(c + 1) * KK];
            float w2 = wk[(c + 2) * KK], w3 = wk[(c + 3) * KK];
#pragma unroll
            for (int t = 0; t < 8; ++t) {
                const float4 s = *(const float4*)&samp[t][c];
                acc[t] = fmaf(s.x, w0, acc[t]);
                acc[t] = fmaf(s.y, w1, acc[t]);
                acc[t] = fmaf(s.z, w2, acc[t]);
                acc[t] = fmaf(s.w, w3, acc[t]);
            }
        }
    }
#pragma unroll
    for (int t = 0; t < 8; ++t)
        out[(((size_t)n * COUT + tid) * HO + ho) * WO + wo0 + t] = acc[t];
}

extern "C" void kernel_launch(void* const* d_in, const int* in_sizes, int n_in,
                              void* d_out, int out_size, void* d_ws, size_t ws_size,
                              hipStream_t stream) {
    const float* inp = (const float*)d_in[0];
    const float* off = (const float*)d_in[1];
    const float* wgt = (const float*)d_in[2];
    float* out = (float*)d_out;

    const size_t img_bytes = (size_t)NN * HH * WW * CIN * 2;
    const size_t wp_bytes  = (size_t)KSTEPS * 16 * 64 * 8 * 2;

    if (ws_size >= img_bytes + wp_bytes) {
        unsigned short* imgB  = (unsigned short*)d_ws;
        unsigned short* wPack = (unsigned short*)((char*)d_ws + img_bytes);
        to_nhwc_f16<<<NN * HH, 256, 0, stream>>>(inp, imgB);
        w_pack<<<(KSTEPS * 16 * 64 * 8) / 256, 256, 0, stream>>>(wgt, wPack);
        deform_mfma<<<PTOT / BM, 512, 0, stream>>>(imgB, off, wPack, out);
    } else {
        deform_fallback<<<PTOT / 8, 256, 0, stream>>>(inp, off, wgt, out);
    }
}